// Round 5
// baseline (217.732 us; speedup 1.0000x reference)
//
#include <hip/hip_runtime.h>
#include <hip/hip_fp16.h>

// DecompGrid, round 5: fp16 channel-last tables (round 4) + spatial counting
// sort of points into 4096 superblock buckets + XCD-chunked sampler dispatch.
// Sorted points give the grid gather L1/L2 locality (per-XCD slab ~1.8 MB
// < 4 MB L2), converting ~276 MB of HBM gather traffic into cache hits.

#define GLO 63
#define GN  65
#define PLO 127
#define PN  129
#define NBUCK 4096            // 16^3 superblocks of 4^3 grid cells

static constexpr size_t SUBG_H = (size_t)GN * GN * GN * 16;  // halves
static constexpr size_t SUBP_H = (size_t)PN * PN * 16;
static constexpr size_t SUBL_H = 64 * 16;
static constexpr size_t WS_HALVES = SUBG_H + 3 * SUBP_H + SUBL_H;

static inline size_t align256(size_t x) { return (x + 255) & ~(size_t)255; }

struct Axis { int base; float u0, u1; };

__device__ __forceinline__ Axis make_axis(float p, int size) {
    float f  = floorf(p);
    float w  = p - f;
    float fs = (float)(size - 1);
    int i0 = (int)fminf(fmaxf(f,        0.0f), fs);
    int i1 = (int)fminf(fmaxf(f + 1.0f, 0.0f), fs);
    int base = (i0 <= size - 2) ? i0 : (size - 2);
    Axis a;
    a.base = base;
    float w0 = 1.0f - w;
    a.u0 = (i0 == base ? w0 : 0.0f) + (i1 == base ? w : 0.0f);
    a.u1 = (i0 == base ? 0.0f : w0) + (i1 == base ? 0.0f : w);
    return a;
}

__device__ __forceinline__ int bucket_of(float4 xv) {
    int gx = (int)floorf((xv.x + 1.0f) * 0.5f * 127.0f);
    int gy = (int)floorf((xv.y + 1.0f) * 0.5f * 127.0f);
    int gz = (int)floorf((xv.z + 1.0f) * 0.5f * 127.0f);
    int lx = min(max(gx - GLO, 0), GN - 2) >> 2;   // 0..15
    int ly = min(max(gy - GLO, 0), GN - 2) >> 2;
    int lz = min(max(gz - GLO, 0), GN - 2) >> 2;
    return (lz * 16 + ly) * 16 + lx;
}

struct f8 { float v[8]; };

__device__ __forceinline__ f8 load8h(const __half* p) {
    float4 r = *reinterpret_cast<const float4*>(p);
    union { float4 f; __half2 h[4]; } u; u.f = r;
    f8 o;
    #pragma unroll
    for (int i = 0; i < 4; ++i) {
        float2 t = __half22float2(u.h[i]);
        o.v[2 * i] = t.x; o.v[2 * i + 1] = t.y;
    }
    return o;
}

__device__ __forceinline__ f8 lerp_pair(const __half* p, float u0, float u1) {
    f8 a = load8h(p), b = load8h(p + 16);
    f8 o;
    #pragma unroll
    for (int j = 0; j < 8; ++j) o.v[j] = fmaf(a.v[j], u0, b.v[j] * u1);
    return o;
}

// Per-point, per-8-channel-group sampling from fp16 tables.
__device__ __forceinline__ void sample_point(
    float4 xv, const __half* __restrict__ ws, int c8,
    f8& spatial, f8& param)
{
    Axis gx = make_axis((xv.x + 1.0f) * 0.5f * 127.0f, 128);
    Axis gy = make_axis((xv.y + 1.0f) * 0.5f * 127.0f, 128);
    Axis gz = make_axis((xv.z + 1.0f) * 0.5f * 127.0f, 128);
    Axis q0 = make_axis((xv.x + 1.0f) * 0.5f * 255.0f, 256);
    Axis q1 = make_axis((xv.y + 1.0f) * 0.5f * 255.0f, 256);
    Axis q2 = make_axis((xv.z + 1.0f) * 0.5f * 255.0f, 256);
    Axis lx = make_axis(xv.w * 63.0f, 64);

    int gxb = min(max(gx.base - GLO, 0), GN - 2);
    int gyb = min(max(gy.base - GLO, 0), GN - 2);
    int gzb = min(max(gz.base - GLO, 0), GN - 2);
    int c0b = min(max(q0.base - PLO, 0), PN - 2);
    int c1b = min(max(q1.base - PLO, 0), PN - 2);
    int c2b = min(max(q2.base - PLO, 0), PN - 2);

    const __half* g = ws + (((size_t)gzb * GN + gyb) * GN + gxb) * 16 + c8;
    const size_t YS = (size_t)GN * 16, ZS = (size_t)GN * GN * 16;
    float w00 = gz.u0 * gy.u0, w01 = gz.u0 * gy.u1;
    float w10 = gz.u1 * gy.u0, w11 = gz.u1 * gy.u1;
    f8 e0 = lerp_pair(g,           gx.u0, gx.u1);
    f8 e1 = lerp_pair(g + YS,      gx.u0, gx.u1);
    f8 e2 = lerp_pair(g + ZS,      gx.u0, gx.u1);
    f8 e3 = lerp_pair(g + ZS + YS, gx.u0, gx.u1);
    f8 tri;
    #pragma unroll
    for (int j = 0; j < 8; ++j)
        tri.v[j] = fmaf(e3.v[j], w11, fmaf(e2.v[j], w10,
                   fmaf(e1.v[j], w01, e0.v[j] * w00)));

    const __half* P0 = ws + SUBG_H;
    const __half* P1 = P0 + SUBP_H;
    const __half* P2 = P1 + SUBP_H;
    const size_t RS = (size_t)PN * 16;

    const __half* pa = P0 + ((size_t)c2b * PN + c1b) * 16 + c8;
    f8 r0 = lerp_pair(pa,      q1.u0, q1.u1);
    f8 r1 = lerp_pair(pa + RS, q1.u0, q1.u1);
    const __half* pb = P1 + ((size_t)c2b * PN + c0b) * 16 + c8;
    f8 s0 = lerp_pair(pb,      q0.u0, q0.u1);
    f8 s1 = lerp_pair(pb + RS, q0.u0, q0.u1);
    const __half* pc = P2 + ((size_t)c1b * PN + c0b) * 16 + c8;
    f8 t0 = lerp_pair(pc,      q0.u0, q0.u1);
    f8 t1 = lerp_pair(pc + RS, q0.u0, q0.u1);
    const __half* lp = P2 + SUBP_H + (size_t)lx.base * 16 + c8;
    param = lerp_pair(lp, lx.u0, lx.u1);

    #pragma unroll
    for (int j = 0; j < 8; ++j) {
        float v0 = fmaf(r0.v[j], q2.u0, r1.v[j] * q2.u1);
        float v1 = fmaf(s0.v[j], q2.u0, s1.v[j] * q2.u1);
        float v2 = fmaf(t0.v[j], q1.u0, t1.v[j] * q1.u1);
        spatial.v[j] = tri.v[j] * v0 * v1 * v2;
    }
}

// ---------------- re-layout: f32 inputs -> fp16 channel-last ws ----------------
__global__ __launch_bounds__(256) void relayout_kernel(
    const float* __restrict__ grid3d, const float* __restrict__ p0,
    const float* __restrict__ p1, const float* __restrict__ p2,
    const float* __restrict__ line0, __half* __restrict__ ws)
{
    int idx = blockIdx.x * blockDim.x + threadIdx.x;
    int c = idx & 15;
    int t = idx >> 4;
    const int GT = GN * GN * GN;
    const int PT = PN * PN;
    if (t < GT) {
        int xx = t % GN; int t2 = t / GN;
        int yy = t2 % GN; int zz = t2 / GN;
        ws[idx] = __float2half(grid3d[c * (128 * 128 * 128)
                    + (GLO + zz) * (128 * 128) + (GLO + yy) * 128 + (GLO + xx)]);
        return;
    }
    t -= GT;
    __half* wp = ws + SUBG_H;
    if (t < 3 * PT) {
        int pl = t / PT; int u = t - pl * PT;
        int cc = u % PN; int r = u / PN;
        const float* src = pl == 0 ? p0 : (pl == 1 ? p1 : p2);
        wp[(size_t)pl * SUBP_H + (size_t)u * 16 + c] =
            __float2half(src[c * 65536 + (PLO + r) * 256 + (PLO + cc)]);
        return;
    }
    t -= 3 * PT;
    if (t < 64) {
        wp[3 * SUBP_H + t * 16 + c] = __float2half(line0[c * 64 + t]);
    }
}

// ---------------- sort passes ----------------
__global__ __launch_bounds__(256) void zero_hist_kernel(int* __restrict__ hist) {
    int i = blockIdx.x * blockDim.x + threadIdx.x;
    if (i < NBUCK) hist[i] = 0;
}

__global__ __launch_bounds__(256) void count_kernel(
    const float4* __restrict__ x, int* __restrict__ hist, int N)
{
    int i = blockIdx.x * blockDim.x + threadIdx.x;
    if (i >= N) return;
    atomicAdd(&hist[bucket_of(x[i])], 1);
}

// single block, 512 threads, 8 entries each: exclusive scan hist -> cursor
__global__ __launch_bounds__(512) void scan_kernel(
    const int* __restrict__ hist, int* __restrict__ cursor)
{
    __shared__ int sums[512];
    int t = threadIdx.x;
    int base = t * 8;
    int local[8];
    int s = 0;
    #pragma unroll
    for (int j = 0; j < 8; ++j) { local[j] = hist[base + j]; s += local[j]; }
    sums[t] = s;
    __syncthreads();
    for (int d = 1; d < 512; d <<= 1) {
        int v = (t >= d) ? sums[t - d] : 0;
        __syncthreads();
        sums[t] += v;
        __syncthreads();
    }
    int run = sums[t] - s;
    #pragma unroll
    for (int j = 0; j < 8; ++j) { cursor[base + j] = run; run += local[j]; }
}

__global__ __launch_bounds__(256) void scatter_kernel(
    const float4* __restrict__ x, int* __restrict__ cursor,
    float4* __restrict__ sx, int* __restrict__ sidx, int N)
{
    int i = blockIdx.x * blockDim.x + threadIdx.x;
    if (i >= N) return;
    float4 xv = x[i];
    int pos = atomicAdd(&cursor[bucket_of(xv)], 1);
    sx[pos] = xv;
    sidx[pos] = i;
}

// ---------------- sampler over sorted points, XCD-chunked ----------------
__global__ __launch_bounds__(256) void sample_sorted_kernel(
    const float4* __restrict__ sx, const int* __restrict__ sidx,
    const __half* __restrict__ ws, float* __restrict__ out, int N)
{
    // bijective XCD swizzle (m204): contiguous sorted chunks per XCD
    int nb = gridDim.x;
    int obid = blockIdx.x;
    int q = nb >> 3, r = nb & 7;
    int xcd = obid & 7, seq = obid >> 3;
    int bid = (xcd < r ? xcd * (q + 1) : r * (q + 1) + (xcd - r) * q) + seq;

    int li = bid * 128 + (threadIdx.x >> 1);   // point slot in sorted order
    if (li >= N) return;
    int c8 = (threadIdx.x & 1) * 8;

    float4 xv = sx[li];
    int n = sidx[li];

    f8 spatial, param;
    sample_point(xv, ws, c8, spatial, param);

    float* o = out + (size_t)n * 32 + c8;
    *reinterpret_cast<float4*>(o) =
        make_float4(spatial.v[0], spatial.v[1], spatial.v[2], spatial.v[3]);
    *reinterpret_cast<float4*>(o + 4) =
        make_float4(spatial.v[4], spatial.v[5], spatial.v[6], spatial.v[7]);
    *reinterpret_cast<float4*>(o + 16) =
        make_float4(param.v[0], param.v[1], param.v[2], param.v[3]);
    *reinterpret_cast<float4*>(o + 20) =
        make_float4(param.v[4], param.v[5], param.v[6], param.v[7]);
}

// ---------------- fallback: round-4 unsorted sampler ----------------
__global__ __launch_bounds__(256) void sample_unsorted_kernel(
    const float* __restrict__ x, const __half* __restrict__ ws,
    float* __restrict__ out, int N)
{
    int gid = blockIdx.x * blockDim.x + threadIdx.x;
    int n = gid >> 1;
    if (n >= N) return;
    int c8 = (gid & 1) * 8;
    float4 xv = reinterpret_cast<const float4*>(x)[n];
    f8 spatial, param;
    sample_point(xv, ws, c8, spatial, param);
    float* o = out + (size_t)n * 32 + c8;
    *reinterpret_cast<float4*>(o) =
        make_float4(spatial.v[0], spatial.v[1], spatial.v[2], spatial.v[3]);
    *reinterpret_cast<float4*>(o + 4) =
        make_float4(spatial.v[4], spatial.v[5], spatial.v[6], spatial.v[7]);
    *reinterpret_cast<float4*>(o + 16) =
        make_float4(param.v[0], param.v[1], param.v[2], param.v[3]);
    *reinterpret_cast<float4*>(o + 20) =
        make_float4(param.v[4], param.v[5], param.v[6], param.v[7]);
}

// ---------------- last-resort direct kernel (no ws) ----------------
__global__ __launch_bounds__(256) void direct_kernel(
    const float* __restrict__ x,
    const float* __restrict__ grid3d, const float* __restrict__ p0,
    const float* __restrict__ p1, const float* __restrict__ p2,
    const float* __restrict__ line0, float* __restrict__ out, int N)
{
    int n = blockIdx.x * blockDim.x + threadIdx.x;
    if (n >= N) return;
    float4 xv = reinterpret_cast<const float4*>(x)[n];
    Axis gx = make_axis((xv.x + 1.0f) * 0.5f * 127.0f, 128);
    Axis gy = make_axis((xv.y + 1.0f) * 0.5f * 127.0f, 128);
    Axis gz = make_axis((xv.z + 1.0f) * 0.5f * 127.0f, 128);
    Axis q0 = make_axis((xv.x + 1.0f) * 0.5f * 255.0f, 256);
    Axis q1 = make_axis((xv.y + 1.0f) * 0.5f * 255.0f, 256);
    Axis q2 = make_axis((xv.z + 1.0f) * 0.5f * 255.0f, 256);
    Axis lx = make_axis(xv.w * 63.0f, 64);
    const int GS = 128 * 128 * 128, PS = 256 * 256, ZS = 128 * 128;
    int gb  = (gz.base * 128 + gy.base) * 128 + gx.base;
    int b0b = q2.base * 256 + q1.base;
    int b1b = q2.base * 256 + q0.base;
    int b2b = q1.base * 256 + q0.base;
    float res[32];
    #pragma unroll
    for (int c = 0; c < 16; ++c) {
        const float* g = grid3d + c * GS + gb;
        float d00 = g[0]        * gx.u0 + g[1]        * gx.u1;
        float d01 = g[128]      * gx.u0 + g[129]      * gx.u1;
        float d10 = g[ZS]       * gx.u0 + g[ZS + 1]   * gx.u1;
        float d11 = g[ZS + 128] * gx.u0 + g[ZS + 129] * gx.u1;
        float tri = gz.u0 * (gy.u0 * d00 + gy.u1 * d01)
                  + gz.u1 * (gy.u0 * d10 + gy.u1 * d11);
        const float* a = p0 + c * PS + b0b;
        float v0 = q2.u0 * (a[0] * q1.u0 + a[1] * q1.u1)
                 + q2.u1 * (a[256] * q1.u0 + a[257] * q1.u1);
        const float* b = p1 + c * PS + b1b;
        float v1 = q2.u0 * (b[0] * q0.u0 + b[1] * q0.u1)
                 + q2.u1 * (b[256] * q0.u0 + b[257] * q0.u1);
        const float* d = p2 + c * PS + b2b;
        float v2 = q1.u0 * (d[0] * q0.u0 + d[1] * q0.u1)
                 + q1.u1 * (d[256] * q0.u0 + d[257] * q0.u1);
        const float* ln = line0 + c * 64 + lx.base;
        res[16 + c] = ln[0] * lx.u0 + ln[1] * lx.u1;
        res[c]      = tri * v0 * v1 * v2;
    }
    float4* o4 = reinterpret_cast<float4*>(out + (size_t)n * 32);
    #pragma unroll
    for (int i = 0; i < 8; ++i)
        o4[i] = make_float4(res[i*4], res[i*4+1], res[i*4+2], res[i*4+3]);
}

extern "C" void kernel_launch(void* const* d_in, const int* in_sizes, int n_in,
                              void* d_out, int out_size, void* d_ws, size_t ws_size,
                              hipStream_t stream) {
    const float* x      = (const float*)d_in[0];
    const float* grid3d = (const float*)d_in[1];
    const float* p0     = (const float*)d_in[2];
    const float* p1     = (const float*)d_in[3];
    const float* p2     = (const float*)d_in[4];
    const float* line0  = (const float*)d_in[5];
    float* out = (float*)d_out;
    int N = in_sizes[0] / 4;

    // ws layout
    size_t tab_bytes  = align256(WS_HALVES * sizeof(__half));
    size_t hist_off   = tab_bytes;
    size_t cursor_off = hist_off + NBUCK * sizeof(int);
    size_t sx_off     = align256(cursor_off + NBUCK * sizeof(int));
    size_t sidx_off   = sx_off + (size_t)N * 16;
    size_t need_sort  = sidx_off + (size_t)N * 4;
    size_t need_tab   = WS_HALVES * sizeof(__half);

    if (ws_size >= need_sort) {
        char* wsb = (char*)d_ws;
        __half* tab   = (__half*)wsb;
        int*    hist  = (int*)(wsb + hist_off);
        int*    cur   = (int*)(wsb + cursor_off);
        float4* sxp   = (float4*)(wsb + sx_off);
        int*    sidx  = (int*)(wsb + sidx_off);
        const float4* x4 = (const float4*)x;

        relayout_kernel<<<(int)((WS_HALVES + 255) / 256), 256, 0, stream>>>(
            grid3d, p0, p1, p2, line0, tab);
        zero_hist_kernel<<<(NBUCK + 255) / 256, 256, 0, stream>>>(hist);
        count_kernel<<<(N + 255) / 256, 256, 0, stream>>>(x4, hist, N);
        scan_kernel<<<1, 512, 0, stream>>>(hist, cur);
        scatter_kernel<<<(N + 255) / 256, 256, 0, stream>>>(x4, cur, sxp, sidx, N);
        int blocks = (N + 127) / 128;
        sample_sorted_kernel<<<blocks, 256, 0, stream>>>(sxp, sidx, tab, out, N);
    } else if (ws_size >= need_tab) {
        __half* tab = (__half*)d_ws;
        relayout_kernel<<<(int)((WS_HALVES + 255) / 256), 256, 0, stream>>>(
            grid3d, p0, p1, p2, line0, tab);
        long long tot = (long long)N * 2;
        sample_unsorted_kernel<<<(int)((tot + 255) / 256), 256, 0, stream>>>(
            x, tab, out, N);
    } else {
        direct_kernel<<<(N + 255) / 256, 256, 0, stream>>>(
            x, grid3d, p0, p1, p2, line0, out, N);
    }
}

// Round 6
// 129.764 us; speedup vs baseline: 1.6779x; 1.6779x over previous
//
#include <hip/hip_runtime.h>
#include <hip/hip_fp16.h>

// DecompGrid, round 6: fp16 channel-last tables + ATOMIC-FREE counting sort
// (LDS-private hists, streaming scan, LDS-rank scatter) + XCD-chunked sorted
// sampler. Round 5's global-atomic sort (1M contended atomicAdds x2) cost
// ~85 us; this sort is ~60 MB of streaming traffic.

#define GLO 63
#define GN  65
#define PLO 127
#define PN  129
#define NBUCK 4096            // 16^3 superblocks of 4^3 grid cells
#define NBLK  256             // sort blocks (chunked over points)

static constexpr size_t SUBG_H = (size_t)GN * GN * GN * 16;  // halves
static constexpr size_t SUBP_H = (size_t)PN * PN * 16;
static constexpr size_t SUBL_H = 64 * 16;
static constexpr size_t WS_HALVES = SUBG_H + 3 * SUBP_H + SUBL_H;

static inline size_t align256(size_t x) { return (x + 255) & ~(size_t)255; }

struct Axis { int base; float u0, u1; };

__device__ __forceinline__ Axis make_axis(float p, int size) {
    float f  = floorf(p);
    float w  = p - f;
    float fs = (float)(size - 1);
    int i0 = (int)fminf(fmaxf(f,        0.0f), fs);
    int i1 = (int)fminf(fmaxf(f + 1.0f, 0.0f), fs);
    int base = (i0 <= size - 2) ? i0 : (size - 2);
    Axis a;
    a.base = base;
    float w0 = 1.0f - w;
    a.u0 = (i0 == base ? w0 : 0.0f) + (i1 == base ? w : 0.0f);
    a.u1 = (i0 == base ? 0.0f : w0) + (i1 == base ? 0.0f : w);
    return a;
}

__device__ __forceinline__ int bucket_of(float4 xv) {
    int gx = (int)floorf((xv.x + 1.0f) * 0.5f * 127.0f);
    int gy = (int)floorf((xv.y + 1.0f) * 0.5f * 127.0f);
    int gz = (int)floorf((xv.z + 1.0f) * 0.5f * 127.0f);
    int lx = min(max(gx - GLO, 0), GN - 2) >> 2;   // 0..15
    int ly = min(max(gy - GLO, 0), GN - 2) >> 2;
    int lz = min(max(gz - GLO, 0), GN - 2) >> 2;
    return (lz * 16 + ly) * 16 + lx;
}

struct f8 { float v[8]; };

__device__ __forceinline__ f8 load8h(const __half* p) {
    float4 r = *reinterpret_cast<const float4*>(p);
    union { float4 f; __half2 h[4]; } u; u.f = r;
    f8 o;
    #pragma unroll
    for (int i = 0; i < 4; ++i) {
        float2 t = __half22float2(u.h[i]);
        o.v[2 * i] = t.x; o.v[2 * i + 1] = t.y;
    }
    return o;
}

__device__ __forceinline__ f8 lerp_pair(const __half* p, float u0, float u1) {
    f8 a = load8h(p), b = load8h(p + 16);
    f8 o;
    #pragma unroll
    for (int j = 0; j < 8; ++j) o.v[j] = fmaf(a.v[j], u0, b.v[j] * u1);
    return o;
}

__device__ __forceinline__ void sample_point(
    float4 xv, const __half* __restrict__ ws, int c8,
    f8& spatial, f8& param)
{
    Axis gx = make_axis((xv.x + 1.0f) * 0.5f * 127.0f, 128);
    Axis gy = make_axis((xv.y + 1.0f) * 0.5f * 127.0f, 128);
    Axis gz = make_axis((xv.z + 1.0f) * 0.5f * 127.0f, 128);
    Axis q0 = make_axis((xv.x + 1.0f) * 0.5f * 255.0f, 256);
    Axis q1 = make_axis((xv.y + 1.0f) * 0.5f * 255.0f, 256);
    Axis q2 = make_axis((xv.z + 1.0f) * 0.5f * 255.0f, 256);
    Axis lx = make_axis(xv.w * 63.0f, 64);

    int gxb = min(max(gx.base - GLO, 0), GN - 2);
    int gyb = min(max(gy.base - GLO, 0), GN - 2);
    int gzb = min(max(gz.base - GLO, 0), GN - 2);
    int c0b = min(max(q0.base - PLO, 0), PN - 2);
    int c1b = min(max(q1.base - PLO, 0), PN - 2);
    int c2b = min(max(q2.base - PLO, 0), PN - 2);

    const __half* g = ws + (((size_t)gzb * GN + gyb) * GN + gxb) * 16 + c8;
    const size_t YS = (size_t)GN * 16, ZS = (size_t)GN * GN * 16;
    float w00 = gz.u0 * gy.u0, w01 = gz.u0 * gy.u1;
    float w10 = gz.u1 * gy.u0, w11 = gz.u1 * gy.u1;
    f8 e0 = lerp_pair(g,           gx.u0, gx.u1);
    f8 e1 = lerp_pair(g + YS,      gx.u0, gx.u1);
    f8 e2 = lerp_pair(g + ZS,      gx.u0, gx.u1);
    f8 e3 = lerp_pair(g + ZS + YS, gx.u0, gx.u1);
    f8 tri;
    #pragma unroll
    for (int j = 0; j < 8; ++j)
        tri.v[j] = fmaf(e3.v[j], w11, fmaf(e2.v[j], w10,
                   fmaf(e1.v[j], w01, e0.v[j] * w00)));

    const __half* P0 = ws + SUBG_H;
    const __half* P1 = P0 + SUBP_H;
    const __half* P2 = P1 + SUBP_H;
    const size_t RS = (size_t)PN * 16;

    const __half* pa = P0 + ((size_t)c2b * PN + c1b) * 16 + c8;
    f8 r0 = lerp_pair(pa,      q1.u0, q1.u1);
    f8 r1 = lerp_pair(pa + RS, q1.u0, q1.u1);
    const __half* pb = P1 + ((size_t)c2b * PN + c0b) * 16 + c8;
    f8 s0 = lerp_pair(pb,      q0.u0, q0.u1);
    f8 s1 = lerp_pair(pb + RS, q0.u0, q0.u1);
    const __half* pc = P2 + ((size_t)c1b * PN + c0b) * 16 + c8;
    f8 t0 = lerp_pair(pc,      q0.u0, q0.u1);
    f8 t1 = lerp_pair(pc + RS, q0.u0, q0.u1);
    const __half* lp = P2 + SUBP_H + (size_t)lx.base * 16 + c8;
    param = lerp_pair(lp, lx.u0, lx.u1);

    #pragma unroll
    for (int j = 0; j < 8; ++j) {
        float v0 = fmaf(r0.v[j], q2.u0, r1.v[j] * q2.u1);
        float v1 = fmaf(s0.v[j], q2.u0, s1.v[j] * q2.u1);
        float v2 = fmaf(t0.v[j], q1.u0, t1.v[j] * q1.u1);
        spatial.v[j] = tri.v[j] * v0 * v1 * v2;
    }
}

// ---------------- re-layout: f32 inputs -> fp16 channel-last ws ----------------
__global__ __launch_bounds__(256) void relayout_kernel(
    const float* __restrict__ grid3d, const float* __restrict__ p0,
    const float* __restrict__ p1, const float* __restrict__ p2,
    const float* __restrict__ line0, __half* __restrict__ ws)
{
    int idx = blockIdx.x * blockDim.x + threadIdx.x;
    int c = idx & 15;
    int t = idx >> 4;
    const int GT = GN * GN * GN;
    const int PT = PN * PN;
    if (t < GT) {
        int xx = t % GN; int t2 = t / GN;
        int yy = t2 % GN; int zz = t2 / GN;
        ws[idx] = __float2half(grid3d[c * (128 * 128 * 128)
                    + (GLO + zz) * (128 * 128) + (GLO + yy) * 128 + (GLO + xx)]);
        return;
    }
    t -= GT;
    __half* wp = ws + SUBG_H;
    if (t < 3 * PT) {
        int pl = t / PT; int u = t - pl * PT;
        int cc = u % PN; int r = u / PN;
        const float* src = pl == 0 ? p0 : (pl == 1 ? p1 : p2);
        wp[(size_t)pl * SUBP_H + (size_t)u * 16 + c] =
            __float2half(src[c * 65536 + (PLO + r) * 256 + (PLO + cc)]);
        return;
    }
    t -= 3 * PT;
    if (t < 64) {
        wp[3 * SUBP_H + t * 16 + c] = __float2half(line0[c * 64 + t]);
    }
}

// ---------------- atomic-free counting sort ----------------
// K1: per-block LDS histogram over a contiguous point chunk -> ghist[blk][b]
__global__ __launch_bounds__(256) void hist_kernel(
    const float4* __restrict__ x, int* __restrict__ ghist, int N, int chunk)
{
    __shared__ int lh[NBUCK];
    int blk = blockIdx.x, tid = threadIdx.x;
    #pragma unroll
    for (int k = tid; k < NBUCK; k += 256) lh[k] = 0;
    __syncthreads();
    int lo = blk * chunk, hi = min(lo + chunk, N);
    for (int i = lo + tid; i < hi; i += 256)
        atomicAdd(&lh[bucket_of(x[i])], 1);
    __syncthreads();
    int* gh = ghist + (size_t)blk * NBUCK;
    #pragma unroll
    for (int k = tid; k < NBUCK; k += 256) gh[k] = lh[k];
}

// K2a: per-bucket totals across blocks. 16 blocks x 256 thr, thread = bucket.
__global__ __launch_bounds__(256) void btot_kernel(
    const int* __restrict__ ghist, int* __restrict__ gtot)
{
    int b = blockIdx.x * 256 + threadIdx.x;
    int s = 0;
    for (int blk = 0; blk < NBLK; ++blk) s += ghist[(size_t)blk * NBUCK + b];
    gtot[b] = s;
}

// K2b: exclusive scan of gtot[4096] -> gbkt[4096]. 1 block, 1024 threads.
__global__ __launch_bounds__(1024) void scan_kernel(
    const int* __restrict__ gtot, int* __restrict__ gbkt)
{
    __shared__ int sums[1024];
    int t = threadIdx.x;
    int base = t * 4;
    int l0 = gtot[base], l1 = gtot[base + 1], l2 = gtot[base + 2], l3 = gtot[base + 3];
    int s = l0 + l1 + l2 + l3;
    sums[t] = s;
    __syncthreads();
    for (int d = 1; d < 1024; d <<= 1) {
        int v = (t >= d) ? sums[t - d] : 0;
        __syncthreads();
        sums[t] += v;
        __syncthreads();
    }
    int run = sums[t] - s;
    gbkt[base] = run;           run += l0;
    gbkt[base + 1] = run;       run += l1;
    gbkt[base + 2] = run;       run += l2;
    gbkt[base + 3] = run;
}

// K2c: absolute per-(block,bucket) base. Same shape as K2a.
__global__ __launch_bounds__(256) void base_kernel(
    const int* __restrict__ ghist, const int* __restrict__ gbkt,
    int* __restrict__ gbase)
{
    int b = blockIdx.x * 256 + threadIdx.x;
    int run = gbkt[b];
    for (int blk = 0; blk < NBLK; ++blk) {
        size_t o = (size_t)blk * NBUCK + b;
        int v = ghist[o];
        gbase[o] = run;
        run += v;
    }
}

// K3: scatter with LDS-computed local ranks (no global atomics).
__global__ __launch_bounds__(256) void scatter_kernel(
    const float4* __restrict__ x, const int* __restrict__ gbase,
    float4* __restrict__ sx, int* __restrict__ sidx, int N, int chunk)
{
    __shared__ int lh[NBUCK];
    int blk = blockIdx.x, tid = threadIdx.x;
    #pragma unroll
    for (int k = tid; k < NBUCK; k += 256) lh[k] = 0;
    __syncthreads();
    const int* gb = gbase + (size_t)blk * NBUCK;
    int lo = blk * chunk, hi = min(lo + chunk, N);
    for (int i = lo + tid; i < hi; i += 256) {
        float4 xv = x[i];
        int b = bucket_of(xv);
        int rank = atomicAdd(&lh[b], 1);   // LDS atomic: cheap, uncontended
        int pos = gb[b] + rank;
        sx[pos] = xv;
        sidx[pos] = i;
    }
}

// ---------------- sampler over sorted points, XCD-chunked ----------------
__global__ __launch_bounds__(256) void sample_sorted_kernel(
    const float4* __restrict__ sx, const int* __restrict__ sidx,
    const __half* __restrict__ ws, float* __restrict__ out, int N)
{
    // bijective XCD swizzle (m204): contiguous sorted chunks per XCD
    int nb = gridDim.x;
    int obid = blockIdx.x;
    int q = nb >> 3, r = nb & 7;
    int xcd = obid & 7, seq = obid >> 3;
    int bid = (xcd < r ? xcd * (q + 1) : r * (q + 1) + (xcd - r) * q) + seq;

    int li = bid * 128 + (threadIdx.x >> 1);
    if (li >= N) return;
    int c8 = (threadIdx.x & 1) * 8;

    float4 xv = sx[li];
    int n = sidx[li];

    f8 spatial, param;
    sample_point(xv, ws, c8, spatial, param);

    float* o = out + (size_t)n * 32 + c8;
    *reinterpret_cast<float4*>(o) =
        make_float4(spatial.v[0], spatial.v[1], spatial.v[2], spatial.v[3]);
    *reinterpret_cast<float4*>(o + 4) =
        make_float4(spatial.v[4], spatial.v[5], spatial.v[6], spatial.v[7]);
    *reinterpret_cast<float4*>(o + 16) =
        make_float4(param.v[0], param.v[1], param.v[2], param.v[3]);
    *reinterpret_cast<float4*>(o + 20) =
        make_float4(param.v[4], param.v[5], param.v[6], param.v[7]);
}

// ---------------- fallback: round-4 unsorted sampler ----------------
__global__ __launch_bounds__(256) void sample_unsorted_kernel(
    const float* __restrict__ x, const __half* __restrict__ ws,
    float* __restrict__ out, int N)
{
    int gid = blockIdx.x * blockDim.x + threadIdx.x;
    int n = gid >> 1;
    if (n >= N) return;
    int c8 = (gid & 1) * 8;
    float4 xv = reinterpret_cast<const float4*>(x)[n];
    f8 spatial, param;
    sample_point(xv, ws, c8, spatial, param);
    float* o = out + (size_t)n * 32 + c8;
    *reinterpret_cast<float4*>(o) =
        make_float4(spatial.v[0], spatial.v[1], spatial.v[2], spatial.v[3]);
    *reinterpret_cast<float4*>(o + 4) =
        make_float4(spatial.v[4], spatial.v[5], spatial.v[6], spatial.v[7]);
    *reinterpret_cast<float4*>(o + 16) =
        make_float4(param.v[0], param.v[1], param.v[2], param.v[3]);
    *reinterpret_cast<float4*>(o + 20) =
        make_float4(param.v[4], param.v[5], param.v[6], param.v[7]);
}

// ---------------- last-resort direct kernel (no ws) ----------------
__global__ __launch_bounds__(256) void direct_kernel(
    const float* __restrict__ x,
    const float* __restrict__ grid3d, const float* __restrict__ p0,
    const float* __restrict__ p1, const float* __restrict__ p2,
    const float* __restrict__ line0, float* __restrict__ out, int N)
{
    int n = blockIdx.x * blockDim.x + threadIdx.x;
    if (n >= N) return;
    float4 xv = reinterpret_cast<const float4*>(x)[n];
    Axis gx = make_axis((xv.x + 1.0f) * 0.5f * 127.0f, 128);
    Axis gy = make_axis((xv.y + 1.0f) * 0.5f * 127.0f, 128);
    Axis gz = make_axis((xv.z + 1.0f) * 0.5f * 127.0f, 128);
    Axis q0 = make_axis((xv.x + 1.0f) * 0.5f * 255.0f, 256);
    Axis q1 = make_axis((xv.y + 1.0f) * 0.5f * 255.0f, 256);
    Axis q2 = make_axis((xv.z + 1.0f) * 0.5f * 255.0f, 256);
    Axis lx = make_axis(xv.w * 63.0f, 64);
    const int GS = 128 * 128 * 128, PS = 256 * 256, ZS = 128 * 128;
    int gb  = (gz.base * 128 + gy.base) * 128 + gx.base;
    int b0b = q2.base * 256 + q1.base;
    int b1b = q2.base * 256 + q0.base;
    int b2b = q1.base * 256 + q0.base;
    float res[32];
    #pragma unroll
    for (int c = 0; c < 16; ++c) {
        const float* g = grid3d + c * GS + gb;
        float d00 = g[0]        * gx.u0 + g[1]        * gx.u1;
        float d01 = g[128]      * gx.u0 + g[129]      * gx.u1;
        float d10 = g[ZS]       * gx.u0 + g[ZS + 1]   * gx.u1;
        float d11 = g[ZS + 128] * gx.u0 + g[ZS + 129] * gx.u1;
        float tri = gz.u0 * (gy.u0 * d00 + gy.u1 * d01)
                  + gz.u1 * (gy.u0 * d10 + gy.u1 * d11);
        const float* a = p0 + c * PS + b0b;
        float v0 = q2.u0 * (a[0] * q1.u0 + a[1] * q1.u1)
                 + q2.u1 * (a[256] * q1.u0 + a[257] * q1.u1);
        const float* b = p1 + c * PS + b1b;
        float v1 = q2.u0 * (b[0] * q0.u0 + b[1] * q0.u1)
                 + q2.u1 * (b[256] * q0.u0 + b[257] * q0.u1);
        const float* d = p2 + c * PS + b2b;
        float v2 = q1.u0 * (d[0] * q0.u0 + d[1] * q0.u1)
                 + q1.u1 * (d[256] * q0.u0 + d[257] * q0.u1);
        const float* ln = line0 + c * 64 + lx.base;
        res[16 + c] = ln[0] * lx.u0 + ln[1] * lx.u1;
        res[c]      = tri * v0 * v1 * v2;
    }
    float4* o4 = reinterpret_cast<float4*>(out + (size_t)n * 32);
    #pragma unroll
    for (int i = 0; i < 8; ++i)
        o4[i] = make_float4(res[i*4], res[i*4+1], res[i*4+2], res[i*4+3]);
}

extern "C" void kernel_launch(void* const* d_in, const int* in_sizes, int n_in,
                              void* d_out, int out_size, void* d_ws, size_t ws_size,
                              hipStream_t stream) {
    const float* x      = (const float*)d_in[0];
    const float* grid3d = (const float*)d_in[1];
    const float* p0     = (const float*)d_in[2];
    const float* p1     = (const float*)d_in[3];
    const float* p2     = (const float*)d_in[4];
    const float* line0  = (const float*)d_in[5];
    float* out = (float*)d_out;
    int N = in_sizes[0] / 4;

    // ws layout
    size_t tab_off   = 0;
    size_t ghist_off = align256(WS_HALVES * sizeof(__half));
    size_t gtot_off  = ghist_off + (size_t)NBLK * NBUCK * 4;
    size_t gbkt_off  = gtot_off + NBUCK * 4;
    size_t gbase_off = gbkt_off + NBUCK * 4;
    size_t sx_off    = align256(gbase_off + (size_t)NBLK * NBUCK * 4);
    size_t sidx_off  = sx_off + (size_t)N * 16;
    size_t need_sort = sidx_off + (size_t)N * 4;
    size_t need_tab  = WS_HALVES * sizeof(__half);

    if (ws_size >= need_sort) {
        char* wsb = (char*)d_ws;
        __half* tab   = (__half*)(wsb + tab_off);
        int*    ghist = (int*)(wsb + ghist_off);
        int*    gtot  = (int*)(wsb + gtot_off);
        int*    gbkt  = (int*)(wsb + gbkt_off);
        int*    gbase = (int*)(wsb + gbase_off);
        float4* sxp   = (float4*)(wsb + sx_off);
        int*    sidx  = (int*)(wsb + sidx_off);
        const float4* x4 = (const float4*)x;
        int chunk = (N + NBLK - 1) / NBLK;

        relayout_kernel<<<(int)((WS_HALVES + 255) / 256), 256, 0, stream>>>(
            grid3d, p0, p1, p2, line0, tab);
        hist_kernel<<<NBLK, 256, 0, stream>>>(x4, ghist, N, chunk);
        btot_kernel<<<NBUCK / 256, 256, 0, stream>>>(ghist, gtot);
        scan_kernel<<<1, 1024, 0, stream>>>(gtot, gbkt);
        base_kernel<<<NBUCK / 256, 256, 0, stream>>>(ghist, gbkt, gbase);
        scatter_kernel<<<NBLK, 256, 0, stream>>>(x4, gbase, sxp, sidx, N, chunk);
        int blocks = (N + 127) / 128;
        sample_sorted_kernel<<<blocks, 256, 0, stream>>>(sxp, sidx, tab, out, N);
    } else if (ws_size >= need_tab) {
        __half* tab = (__half*)d_ws;
        relayout_kernel<<<(int)((WS_HALVES + 255) / 256), 256, 0, stream>>>(
            grid3d, p0, p1, p2, line0, tab);
        long long tot = (long long)N * 2;
        sample_unsorted_kernel<<<(int)((tot + 255) / 256), 256, 0, stream>>>(
            x, tab, out, N);
    } else {
        direct_kernel<<<(N + 255) / 256, 256, 0, stream>>>(
            x, grid3d, p0, p1, p2, line0, out, N);
    }
}